// Round 1
// baseline (675.475 us; speedup 1.0000x reference)
//
#include <hip/hip_runtime.h>
#include <math.h>

#define FIN 256
#define HID 64
#define NC  16

// ---------------- degree / normalization ----------------

__global__ void k_deg_init(float* __restrict__ deg, int N) {
    int i = blockIdx.x * blockDim.x + threadIdx.x;
    if (i < N) deg[i] = 1.0f;   // self-loop contributes 1 to every node's degree
}

__global__ void k_deg_count(const int* __restrict__ row, float* __restrict__ deg, int E) {
    int e = blockIdx.x * blockDim.x + threadIdx.x;
    if (e < E) atomicAdd(&deg[row[e]], 1.0f);
}

__global__ void k_dinv(const float* __restrict__ deg, float* __restrict__ dinv, int N) {
    int i = blockIdx.x * blockDim.x + threadIdx.x;
    if (i < N) dinv[i] = rsqrtf(deg[i]);   // deg >= 1 always (self loops)
}

// ---------------- GEMM1: h1 = x @ W1   (N x 256) @ (256 x 64) ----------------
// 16 rows per block, 256 threads. W1 (64KB) + x-tile (16x260 padded, ~16.6KB) in LDS.

__global__ __launch_bounds__(256) void k_gemm1(const float* __restrict__ x,
                                               const float* __restrict__ W1,
                                               float* __restrict__ h1) {
    __shared__ float Ws[FIN * HID];        // 64 KB, row-major [k][c]
    __shared__ float xs[16][FIN + 4];      // +4 pad keeps float4 alignment, kills bank conflicts
    const int tid = threadIdx.x;

    // load W1: 16384 floats = 4096 float4
    const float4* W4 = (const float4*)W1;
    float4* Ws4 = (float4*)Ws;
#pragma unroll
    for (int i = 0; i < 16; ++i) Ws4[tid + i * 256] = W4[tid + i * 256];

    // load x tile: 16 rows x 256 = 1024 float4
    const int row0 = blockIdx.x * 16;
    const float4* x4 = (const float4*)(x + (size_t)row0 * FIN);
#pragma unroll
    for (int i = 0; i < 4; ++i) {
        int idx = tid + i * 256;          // float4 index within tile
        int r = idx >> 6;                 // 64 float4 per row
        int q = idx & 63;
        *(float4*)&xs[r][q * 4] = x4[idx];
    }
    __syncthreads();

    const int r  = tid >> 4;              // 0..15 row within tile
    const int c0 = (tid & 15) << 2;       // 4 consecutive output cols
    float4 acc = make_float4(0.f, 0.f, 0.f, 0.f);
    const float* xr = xs[r];
#pragma unroll 4
    for (int k = 0; k < FIN; k += 4) {
        float4 xv = *(const float4*)(xr + k);
        float4 w0 = *(const float4*)(Ws + (k + 0) * HID + c0);
        float4 w1 = *(const float4*)(Ws + (k + 1) * HID + c0);
        float4 w2 = *(const float4*)(Ws + (k + 2) * HID + c0);
        float4 w3 = *(const float4*)(Ws + (k + 3) * HID + c0);
        acc.x += xv.x * w0.x + xv.y * w1.x + xv.z * w2.x + xv.w * w3.x;
        acc.y += xv.x * w0.y + xv.y * w1.y + xv.z * w2.y + xv.w * w3.y;
        acc.z += xv.x * w0.z + xv.y * w1.z + xv.z * w2.z + xv.w * w3.z;
        acc.w += xv.x * w0.w + xv.y * w1.w + xv.z * w2.w + xv.w * w3.w;
    }
    *(float4*)(h1 + (size_t)(row0 + r) * HID + c0) = acc;
}

// ---------------- self-loop init: agg[i] = h[i] * dinv[i]^2 ----------------

__global__ void k_self1(const float* __restrict__ h1, const float* __restrict__ dinv,
                        float* __restrict__ agg1, int N) {
    int t = blockIdx.x * blockDim.x + threadIdx.x;
    if (t < N * HID) {
        int i = t >> 6;
        float d = dinv[i];
        agg1[t] = h1[t] * d * d;
    }
}

__global__ void k_self2(const float* __restrict__ h2, const float* __restrict__ dinv,
                        float* __restrict__ agg2, int N) {
    int t = blockIdx.x * blockDim.x + threadIdx.x;
    if (t < N * NC) {
        int i = t >> 4;
        float d = dinv[i];
        agg2[t] = h2[t] * d * d;
    }
}

// ---------------- scatter1: wave per edge, lane = feature (64) ----------------

__global__ __launch_bounds__(256) void k_scatter1(const int* __restrict__ row,
                                                  const int* __restrict__ col,
                                                  const float* __restrict__ dinv,
                                                  const float* __restrict__ h1,
                                                  float* __restrict__ agg1, int E) {
    int e = blockIdx.x * 4 + (threadIdx.x >> 6);
    int lane = threadIdx.x & 63;
    if (e < E) {
        int r = row[e], c = col[e];
        float nrm = dinv[r] * dinv[c];
        float v = h1[(size_t)c * HID + lane] * nrm;
        atomicAdd(&agg1[(size_t)r * HID + lane], v);
    }
}

// ---------------- scatter2: 16 lanes per edge ----------------

__global__ __launch_bounds__(256) void k_scatter2(const int* __restrict__ row,
                                                  const int* __restrict__ col,
                                                  const float* __restrict__ dinv,
                                                  const float* __restrict__ h2,
                                                  float* __restrict__ agg2, int E) {
    int idx = blockIdx.x * blockDim.x + threadIdx.x;
    int e = idx >> 4;
    int f = idx & 15;
    if (e < E) {
        int r = row[e], c = col[e];
        float nrm = dinv[r] * dinv[c];
        float v = h2[(size_t)c * NC + f] * nrm;
        atomicAdd(&agg2[(size_t)r * NC + f], v);
    }
}

// ---------------- GEMM2 fused: h2 = relu(agg1 + b1) @ W2  (N x 64) @ (64 x 16) ----------------

__global__ __launch_bounds__(256) void k_gemm2(const float* __restrict__ agg1,
                                               const float* __restrict__ b1,
                                               const float* __restrict__ W2,
                                               float* __restrict__ h2) {
    __shared__ float Ws[HID * NC];        // 1024 floats, [k][c]
    __shared__ float hs[16][HID + 4];     // relu'd activations, padded
    const int tid = threadIdx.x;

    // load W2 (1024 floats): 4 each
#pragma unroll
    for (int i = 0; i < 4; ++i) Ws[tid + i * 256] = W2[tid + i * 256];

    const int n0 = blockIdx.x * 16;
    // load agg1 tile: 16 nodes x 64 = 256 float4, apply +b1 then relu
    {
        float4 v = ((const float4*)(agg1 + (size_t)n0 * HID))[tid];
        int n  = tid >> 4;
        int k0 = (tid & 15) << 2;
        float4 bb = *(const float4*)(b1 + k0);
        v.x = fmaxf(v.x + bb.x, 0.f);
        v.y = fmaxf(v.y + bb.y, 0.f);
        v.z = fmaxf(v.z + bb.z, 0.f);
        v.w = fmaxf(v.w + bb.w, 0.f);
        *(float4*)&hs[n][k0] = v;
    }
    __syncthreads();

    const int n = tid >> 4;               // node within tile
    const int c = tid & 15;               // class
    float acc = 0.f;
#pragma unroll
    for (int k = 0; k < HID; ++k) {
        acc += hs[n][k] * Ws[k * NC + c];
    }
    h2[(size_t)(n0 + n) * NC + c] = acc;
}

// ---------------- final: out = log_softmax(agg2 + b2) ----------------

__global__ __launch_bounds__(256) void k_final(const float* __restrict__ agg2,
                                               const float* __restrict__ b2,
                                               float* __restrict__ out, int N) {
    int i = blockIdx.x * blockDim.x + threadIdx.x;
    if (i >= N) return;
    float v[NC];
    const float4* src = (const float4*)(agg2 + (size_t)i * NC);
#pragma unroll
    for (int q = 0; q < 4; ++q) {
        float4 t = src[q];
        v[q * 4 + 0] = t.x + b2[q * 4 + 0];
        v[q * 4 + 1] = t.y + b2[q * 4 + 1];
        v[q * 4 + 2] = t.z + b2[q * 4 + 2];
        v[q * 4 + 3] = t.w + b2[q * 4 + 3];
    }
    float m = v[0];
#pragma unroll
    for (int c = 1; c < NC; ++c) m = fmaxf(m, v[c]);
    float s = 0.f;
#pragma unroll
    for (int c = 0; c < NC; ++c) s += expf(v[c] - m);
    float ls = logf(s);
    float4* dst = (float4*)(out + (size_t)i * NC);
#pragma unroll
    for (int q = 0; q < 4; ++q) {
        float4 t;
        t.x = v[q * 4 + 0] - m - ls;
        t.y = v[q * 4 + 1] - m - ls;
        t.z = v[q * 4 + 2] - m - ls;
        t.w = v[q * 4 + 3] - m - ls;
        dst[q] = t;
    }
}

// ---------------- launch ----------------

extern "C" void kernel_launch(void* const* d_in, const int* in_sizes, int n_in,
                              void* d_out, int out_size, void* d_ws, size_t ws_size,
                              hipStream_t stream) {
    const float* x  = (const float*)d_in[0];
    const int*   ei = (const int*)d_in[1];     // (2, E) int32
    const float* W1 = (const float*)d_in[2];
    const float* b1 = (const float*)d_in[3];
    const float* W2 = (const float*)d_in[4];
    const float* b2 = (const float*)d_in[5];
    float* out = (float*)d_out;

    const int N = in_sizes[0] / FIN;           // 50000
    const int E = in_sizes[1] / 2;             // 1600000
    const int* row = ei;                       // targets
    const int* col = ei + E;                   // sources

    // workspace layout (floats)
    float* ws   = (float*)d_ws;
    float* deg  = ws;                          // N
    float* dinv = deg  + N;                    // N
    float* h1   = dinv + N;                    // N*64
    float* agg1 = h1   + (size_t)N * HID;      // N*64
    float* h2   = agg1 + (size_t)N * HID;      // N*16
    float* agg2 = h2   + (size_t)N * NC;       // N*16

    const int B = 256;

    k_deg_init<<<(N + B - 1) / B, B, 0, stream>>>(deg, N);
    k_deg_count<<<(E + B - 1) / B, B, 0, stream>>>(row, deg, E);
    k_dinv<<<(N + B - 1) / B, B, 0, stream>>>(deg, dinv, N);

    k_gemm1<<<N / 16, B, 0, stream>>>(x, W1, h1);

    k_self1<<<((size_t)N * HID + B - 1) / B, B, 0, stream>>>(h1, dinv, agg1, N);
    k_scatter1<<<(E + 3) / 4, B, 0, stream>>>(row, col, dinv, h1, agg1, E);

    k_gemm2<<<N / 16, B, 0, stream>>>(agg1, b1, W2, h2);

    k_self2<<<((size_t)N * NC + B - 1) / B, B, 0, stream>>>(h2, dinv, agg2, N);
    k_scatter2<<<((size_t)E * NC + B - 1) / B, B, 0, stream>>>(row, col, dinv, h2, agg2, E);

    k_final<<<(N + B - 1) / B, B, 0, stream>>>(agg2, b2, out, N);
}

// Round 7
// 477.948 us; speedup vs baseline: 1.4133x; 1.4133x over previous
//
#include <hip/hip_runtime.h>
#include <math.h>

#define FIN 256
#define HID 64
#define NC  16

// ================= histogram / degree =================

__global__ void k_hist(const int* __restrict__ row, int* __restrict__ cnt, int E) {
    int e = blockIdx.x * blockDim.x + threadIdx.x;
    if (e < E) atomicAdd(&cnt[row[e]], 1);
}

__global__ void k_dinv(const int* __restrict__ cnt, float* __restrict__ dinv, int N) {
    int i = blockIdx.x * blockDim.x + threadIdx.x;
    if (i < N) dinv[i] = rsqrtf((float)(cnt[i] + 1));   // +1 self loop
}

// ================= exclusive scan of cnt -> off (N=50000, 2-level) =================

__global__ void k_scan_block(const int* __restrict__ cnt, int* __restrict__ offtmp,
                             int* __restrict__ bsum, int N) {
    __shared__ int s[256];
    int t = threadIdx.x, i = blockIdx.x * 256 + t;
    int v = (i < N) ? cnt[i] : 0;
    s[t] = v; __syncthreads();
    for (int d = 1; d < 256; d <<= 1) {
        int add = (t >= d) ? s[t - d] : 0;
        __syncthreads();
        s[t] += add;
        __syncthreads();
    }
    if (i < N) offtmp[i] = s[t] - v;          // exclusive within block
    if (t == 255) bsum[blockIdx.x] = s[255];  // block total
}

__global__ void k_scan_bsum(int* __restrict__ bsum, int nb) {
    __shared__ int s[256];
    int t = threadIdx.x;
    int v = (t < nb) ? bsum[t] : 0;
    s[t] = v; __syncthreads();
    for (int d = 1; d < 256; d <<= 1) {
        int add = (t >= d) ? s[t - d] : 0;
        __syncthreads();
        s[t] += add;
        __syncthreads();
    }
    if (t < nb) bsum[t] = s[t] - v;           // exclusive block offsets
}

__global__ void k_off(const int* __restrict__ offtmp, const int* __restrict__ bsum,
                      int* __restrict__ off, int* __restrict__ cur, int N) {
    int i = blockIdx.x * blockDim.x + threadIdx.x;
    if (i < N) {
        int o = offtmp[i] + bsum[i >> 8];
        off[i] = o;
        cur[i] = o;
    }
}

// ================= reorder edges into CSR (by target) =================

__global__ void k_reorder(const int* __restrict__ row, const int* __restrict__ col,
                          const float* __restrict__ dinv, int* __restrict__ cur,
                          int* __restrict__ colS, float* __restrict__ normS, int E) {
    int e = blockIdx.x * blockDim.x + threadIdx.x;
    if (e < E) {
        int r = row[e], c = col[e];
        int p = atomicAdd(&cur[r], 1);
        colS[p] = c;
        normS[p] = dinv[r] * dinv[c];
    }
}

// ================= GEMM1: h1 = x @ W1   (N x 256) @ (256 x 64) =================

__global__ __launch_bounds__(256) void k_gemm1(const float* __restrict__ x,
                                               const float* __restrict__ W1,
                                               float* __restrict__ h1) {
    __shared__ float Ws[FIN * HID];        // 64 KB, [k][c]
    __shared__ float xs[16][FIN + 4];
    const int tid = threadIdx.x;

    const float4* W4 = (const float4*)W1;
    float4* Ws4 = (float4*)Ws;
#pragma unroll
    for (int i = 0; i < 16; ++i) Ws4[tid + i * 256] = W4[tid + i * 256];

    const int row0 = blockIdx.x * 16;
    const float4* x4 = (const float4*)(x + (size_t)row0 * FIN);
#pragma unroll
    for (int i = 0; i < 4; ++i) {
        int idx = tid + i * 256;
        int r = idx >> 6;
        int q = idx & 63;
        *(float4*)&xs[r][q * 4] = x4[idx];
    }
    __syncthreads();

    const int r  = tid >> 4;
    const int c0 = (tid & 15) << 2;
    float4 acc = make_float4(0.f, 0.f, 0.f, 0.f);
    const float* xr = xs[r];
#pragma unroll 4
    for (int k = 0; k < FIN; k += 4) {
        float4 xv = *(const float4*)(xr + k);
        float4 w0 = *(const float4*)(Ws + (k + 0) * HID + c0);
        float4 w1 = *(const float4*)(Ws + (k + 1) * HID + c0);
        float4 w2 = *(const float4*)(Ws + (k + 2) * HID + c0);
        float4 w3 = *(const float4*)(Ws + (k + 3) * HID + c0);
        acc.x += xv.x * w0.x + xv.y * w1.x + xv.z * w2.x + xv.w * w3.x;
        acc.y += xv.x * w0.y + xv.y * w1.y + xv.z * w2.y + xv.w * w3.y;
        acc.z += xv.x * w0.z + xv.y * w1.z + xv.z * w2.z + xv.w * w3.z;
        acc.w += xv.x * w0.w + xv.y * w1.w + xv.z * w2.w + xv.w * w3.w;
    }
    *(float4*)(h1 + (size_t)(row0 + r) * HID + c0) = acc;
}

// ================= agg1: gather-reduce, wave per node, lane = feature =================

__global__ __launch_bounds__(256) void k_agg1(const int* __restrict__ off,
                                              const int* __restrict__ cnt,
                                              const int* __restrict__ colS,
                                              const float* __restrict__ normS,
                                              const float* __restrict__ dinv,
                                              const float* __restrict__ h1,
                                              float* __restrict__ agg1, int N) {
    int i = blockIdx.x * 4 + (threadIdx.x >> 6);
    if (i >= N) return;
    int lane = threadIdx.x & 63;
    int s = off[i], n = cnt[i];
    float di = dinv[i];
    float acc = h1[(size_t)i * HID + lane] * di * di;   // self loop

    int j = 0;
    for (; j + 4 <= n; j += 4) {
        int   c0 = colS[s + j],     c1 = colS[s + j + 1];
        int   c2 = colS[s + j + 2], c3 = colS[s + j + 3];
        float w0 = normS[s + j],     w1 = normS[s + j + 1];
        float w2 = normS[s + j + 2], w3 = normS[s + j + 3];
        acc += h1[(size_t)c0 * HID + lane] * w0;
        acc += h1[(size_t)c1 * HID + lane] * w1;
        acc += h1[(size_t)c2 * HID + lane] * w2;
        acc += h1[(size_t)c3 * HID + lane] * w3;
    }
    for (; j < n; ++j) {
        int c = colS[s + j];
        float w = normS[s + j];
        acc += h1[(size_t)c * HID + lane] * w;
    }
    agg1[(size_t)i * HID + lane] = acc;
}

// ================= GEMM2 fused: h2 = relu(agg1 + b1) @ W2 =================

__global__ __launch_bounds__(256) void k_gemm2(const float* __restrict__ agg1,
                                               const float* __restrict__ b1,
                                               const float* __restrict__ W2,
                                               float* __restrict__ h2) {
    __shared__ float Ws[HID * NC];
    __shared__ float hs[16][HID + 4];
    const int tid = threadIdx.x;

#pragma unroll
    for (int i = 0; i < 4; ++i) Ws[tid + i * 256] = W2[tid + i * 256];

    const int n0 = blockIdx.x * 16;
    {
        float4 v = ((const float4*)(agg1 + (size_t)n0 * HID))[tid];
        int n  = tid >> 4;
        int k0 = (tid & 15) << 2;
        float4 bb = *(const float4*)(b1 + k0);
        v.x = fmaxf(v.x + bb.x, 0.f);
        v.y = fmaxf(v.y + bb.y, 0.f);
        v.z = fmaxf(v.z + bb.z, 0.f);
        v.w = fmaxf(v.w + bb.w, 0.f);
        *(float4*)&hs[n][k0] = v;
    }
    __syncthreads();

    const int n = tid >> 4;
    const int c = tid & 15;
    float acc = 0.f;
#pragma unroll
    for (int k = 0; k < HID; ++k) {
        acc += hs[n][k] * Ws[k * NC + c];
    }
    h2[(size_t)(n0 + n) * NC + c] = acc;
}

// ================= agg2: gather-reduce, wave per node, 16 feats x 4 edges =================

__global__ __launch_bounds__(256) void k_agg2(const int* __restrict__ off,
                                              const int* __restrict__ cnt,
                                              const int* __restrict__ colS,
                                              const float* __restrict__ normS,
                                              const float* __restrict__ dinv,
                                              const float* __restrict__ h2,
                                              float* __restrict__ agg2, int N) {
    int i = blockIdx.x * 4 + (threadIdx.x >> 6);
    if (i >= N) return;
    int lane = threadIdx.x & 63;
    int f = lane & 15;          // feature
    int k = lane >> 4;          // edge phase 0..3
    int s = off[i], n = cnt[i];

    float acc = 0.f;
    for (int j = k; j < n; j += 4) {
        int c = colS[s + j];
        float w = normS[s + j];
        acc += h2[(size_t)c * NC + f] * w;
    }
    acc += __shfl_xor(acc, 16, 64);
    acc += __shfl_xor(acc, 32, 64);
    if (k == 0) {
        float di = dinv[i];
        agg2[(size_t)i * NC + f] = acc + h2[(size_t)i * NC + f] * di * di;
    }
}

// ================= final: out = log_softmax(agg2 + b2) =================

__global__ __launch_bounds__(256) void k_final(const float* __restrict__ agg2,
                                               const float* __restrict__ b2,
                                               float* __restrict__ out, int N) {
    int i = blockIdx.x * blockDim.x + threadIdx.x;
    if (i >= N) return;
    float v[NC];
    const float4* src = (const float4*)(agg2 + (size_t)i * NC);
#pragma unroll
    for (int q = 0; q < 4; ++q) {
        float4 t = src[q];
        v[q * 4 + 0] = t.x + b2[q * 4 + 0];
        v[q * 4 + 1] = t.y + b2[q * 4 + 1];
        v[q * 4 + 2] = t.z + b2[q * 4 + 2];
        v[q * 4 + 3] = t.w + b2[q * 4 + 3];
    }
    float m = v[0];
#pragma unroll
    for (int c = 1; c < NC; ++c) m = fmaxf(m, v[c]);
    float s = 0.f;
#pragma unroll
    for (int c = 0; c < NC; ++c) s += expf(v[c] - m);
    float ls = logf(s);
    float4* dst = (float4*)(out + (size_t)i * NC);
#pragma unroll
    for (int q = 0; q < 4; ++q) {
        float4 t;
        t.x = v[q * 4 + 0] - m - ls;
        t.y = v[q * 4 + 1] - m - ls;
        t.z = v[q * 4 + 2] - m - ls;
        t.w = v[q * 4 + 3] - m - ls;
        dst[q] = t;
    }
}

// ================= launch =================

extern "C" void kernel_launch(void* const* d_in, const int* in_sizes, int n_in,
                              void* d_out, int out_size, void* d_ws, size_t ws_size,
                              hipStream_t stream) {
    const float* x  = (const float*)d_in[0];
    const int*   ei = (const int*)d_in[1];
    const float* W1 = (const float*)d_in[2];
    const float* b1 = (const float*)d_in[3];
    const float* W2 = (const float*)d_in[4];
    const float* b2 = (const float*)d_in[5];
    float* out = (float*)d_out;

    const int N = in_sizes[0] / FIN;        // 50000
    const int E = in_sizes[1] / 2;          // 1600000
    const int* row = ei;                    // targets
    const int* col = ei + E;                // sources

    // ---- workspace layout (all offsets 16B-aligned) ----
    char* w = (char*)d_ws;
    int*   cnt    = (int*)w;                          w += (size_t)N * 4;        // 200000
    int*   off    = (int*)w;                          w += (size_t)N * 4;
    int*   cur    = (int*)w;                          w += (size_t)N * 4;
    int*   offtmp = (int*)w;                          w += (size_t)N * 4;
    int*   bsum   = (int*)w;                          w += 256 * 4;
    int*   colS   = (int*)w;                          w += (size_t)E * 4;
    float* normS  = (float*)w;                        w += (size_t)E * 4;
    float* dinv   = (float*)w;                        w += (size_t)N * 4;
    float* h1     = (float*)w;                        w += (size_t)N * HID * 4;
    float* agg1   = (float*)w;                        w += (size_t)N * HID * 4;
    float* h2     = (float*)w;                        w += (size_t)N * NC * 4;
    float* agg2   = (float*)w;                        w += (size_t)N * NC * 4;

    const int B = 256;
    const int nbN = (N + B - 1) / B;   // 196

    hipMemsetAsync(cnt, 0, (size_t)N * 4, stream);
    k_hist<<<(E + B - 1) / B, B, 0, stream>>>(row, cnt, E);
    k_dinv<<<nbN, B, 0, stream>>>(cnt, dinv, N);

    k_scan_block<<<nbN, B, 0, stream>>>(cnt, offtmp, bsum, N);
    k_scan_bsum<<<1, B, 0, stream>>>(bsum, nbN);
    k_off<<<nbN, B, 0, stream>>>(offtmp, bsum, off, cur, N);

    k_reorder<<<(E + B - 1) / B, B, 0, stream>>>(row, col, dinv, cur, colS, normS, E);

    k_gemm1<<<N / 16, B, 0, stream>>>(x, W1, h1);
    k_agg1<<<(N + 3) / 4, B, 0, stream>>>(off, cnt, colS, normS, dinv, h1, agg1, N);

    k_gemm2<<<N / 16, B, 0, stream>>>(agg1, b1, W2, h2);
    k_agg2<<<(N + 3) / 4, B, 0, stream>>>(off, cnt, colS, normS, dinv, h2, agg2, N);

    k_final<<<nbN, B, 0, stream>>>(agg2, b2, out, N);
}

// Round 9
// 415.334 us; speedup vs baseline: 1.6263x; 1.1508x over previous
//
#include <hip/hip_runtime.h>
#include <math.h>

#define FIN 256
#define HID 64
#define NC  16

// Buckets for the binning sort: 256 nodes per bucket (bucket = node >> 8).
// For N=50000 -> NB=196 buckets (NB <= 256 required).

// ================= histogram / degree =================

__global__ void k_hist(const int* __restrict__ row, int* __restrict__ cnt, int E) {
    int e = blockIdx.x * blockDim.x + threadIdx.x;
    if (e < E) atomicAdd(&cnt[row[e]], 1);
}

__global__ void k_dinv(const int* __restrict__ cnt, float* __restrict__ dinv, int N) {
    int i = blockIdx.x * blockDim.x + threadIdx.x;
    if (i < N) dinv[i] = rsqrtf((float)(cnt[i] + 1));   // +1 self loop
}

// ================= exclusive scan of cnt -> off (2-level) =================

__global__ void k_scan_block(const int* __restrict__ cnt, int* __restrict__ offtmp,
                             int* __restrict__ bsum, int N) {
    __shared__ int s[256];
    int t = threadIdx.x, i = blockIdx.x * 256 + t;
    int v = (i < N) ? cnt[i] : 0;
    s[t] = v; __syncthreads();
    for (int d = 1; d < 256; d <<= 1) {
        int add = (t >= d) ? s[t - d] : 0;
        __syncthreads();
        s[t] += add;
        __syncthreads();
    }
    if (i < N) offtmp[i] = s[t] - v;
    if (t == 255) bsum[blockIdx.x] = s[255];
}

__global__ void k_scan_bsum(int* __restrict__ bsum, int nb) {
    __shared__ int s[256];
    int t = threadIdx.x;
    int v = (t < nb) ? bsum[t] : 0;
    s[t] = v; __syncthreads();
    for (int d = 1; d < 256; d <<= 1) {
        int add = (t >= d) ? s[t - d] : 0;
        __syncthreads();
        s[t] += add;
        __syncthreads();
    }
    if (t < nb) bsum[t] = s[t] - v;
}

__global__ void k_off(const int* __restrict__ offtmp, const int* __restrict__ bsum,
                      int* __restrict__ off, int* __restrict__ cur, int N) {
    int i = blockIdx.x * blockDim.x + threadIdx.x;
    if (i < N) {
        int o = offtmp[i] + bsum[i >> 8];
        off[i] = o;
        cur[i] = o;
    }
}

// bucket start cursors: bucket b covers nodes [b*256, (b+1)*256)
__global__ void k_bstart(const int* __restrict__ off, int* __restrict__ bcur, int NB) {
    int b = threadIdx.x;
    if (b < NB) bcur[b] = off[b << 8];
}

// ================= pass 1: bin edges by bucket into stage (locality-preserving) =================
// Each block: LDS-histogram its 4096-edge chunk by bucket, reserve one contiguous
// run per (block,bucket) with a single global atomicAdd, write (r,c) pairs there.

#define BIN_CHUNK 4096   // 256 threads x 16 edges

__global__ __launch_bounds__(256) void k_bin(const int* __restrict__ row,
                                             const int* __restrict__ col,
                                             int* __restrict__ bcur,
                                             int2* __restrict__ stage, int E) {
    __shared__ unsigned lcnt[256];
    __shared__ unsigned lpos[256];
    const int tid = threadIdx.x;
    const int base = blockIdx.x * BIN_CHUNK;

    lcnt[tid] = 0;
    __syncthreads();

    int      rr[16];
    unsigned myofs[16];
#pragma unroll
    for (int k = 0; k < 16; ++k) {
        int idx = base + tid + k * 256;
        if (idx < E) {
            int r = row[idx];
            rr[k] = r;
            myofs[k] = atomicAdd(&lcnt[r >> 8], 1u);   // LDS atomic, ~21 hits/bucket
        }
    }
    __syncthreads();

    unsigned c = lcnt[tid];
    lpos[tid] = (c > 0) ? (unsigned)atomicAdd(&bcur[tid], (int)c) : 0u;
    __syncthreads();

#pragma unroll
    for (int k = 0; k < 16; ++k) {
        int idx = base + tid + k * 256;
        if (idx < E) {
            int r = rr[k];
            unsigned p = lpos[r >> 8] + myofs[k];
            stage[p] = make_int2(r, col[idx]);        // block-private contiguous runs
        }
    }
}

// ================= pass 2: place staged edges into final CSR position =================
// stage is bucket-ordered -> cur/colS accesses localized to ~32KB regions (L2-absorbed).

__global__ void k_place(const int2* __restrict__ stage, int* __restrict__ cur,
                        int* __restrict__ colS, int E) {
    int e = blockIdx.x * blockDim.x + threadIdx.x;
    if (e < E) {
        int2 rc = stage[e];
        int p = atomicAdd(&cur[rc.x], 1);
        colS[p] = rc.y;
    }
}

// ================= GEMM1: h1 = x @ W1   (N x 256) @ (256 x 64) =================

__global__ __launch_bounds__(256) void k_gemm1(const float* __restrict__ x,
                                               const float* __restrict__ W1,
                                               float* __restrict__ h1) {
    __shared__ float Ws[FIN * HID];        // 64 KB, [k][c]
    __shared__ float xs[16][FIN + 4];
    const int tid = threadIdx.x;

    const float4* W4 = (const float4*)W1;
    float4* Ws4 = (float4*)Ws;
#pragma unroll
    for (int i = 0; i < 16; ++i) Ws4[tid + i * 256] = W4[tid + i * 256];

    const int row0 = blockIdx.x * 16;
    const float4* x4 = (const float4*)(x + (size_t)row0 * FIN);
#pragma unroll
    for (int i = 0; i < 4; ++i) {
        int idx = tid + i * 256;
        int r = idx >> 6;
        int q = idx & 63;
        *(float4*)&xs[r][q * 4] = x4[idx];
    }
    __syncthreads();

    const int r  = tid >> 4;
    const int c0 = (tid & 15) << 2;
    float4 acc = make_float4(0.f, 0.f, 0.f, 0.f);
    const float* xr = xs[r];
#pragma unroll 4
    for (int k = 0; k < FIN; k += 4) {
        float4 xv = *(const float4*)(xr + k);
        float4 w0 = *(const float4*)(Ws + (k + 0) * HID + c0);
        float4 w1 = *(const float4*)(Ws + (k + 1) * HID + c0);
        float4 w2 = *(const float4*)(Ws + (k + 2) * HID + c0);
        float4 w3 = *(const float4*)(Ws + (k + 3) * HID + c0);
        acc.x += xv.x * w0.x + xv.y * w1.x + xv.z * w2.x + xv.w * w3.x;
        acc.y += xv.x * w0.y + xv.y * w1.y + xv.z * w2.y + xv.w * w3.y;
        acc.z += xv.x * w0.z + xv.y * w1.z + xv.z * w2.z + xv.w * w3.z;
        acc.w += xv.x * w0.w + xv.y * w1.w + xv.z * w2.w + xv.w * w3.w;
    }
    *(float4*)(h1 + (size_t)(row0 + r) * HID + c0) = acc;
}

// ================= agg1: gather-reduce, wave per node, lane = feature =================
// out = di * ( di*h1[i] + sum_c dinv[c]*h1[c] )   -- di factored out of the loop

__global__ __launch_bounds__(256) void k_agg1(const int* __restrict__ off,
                                              const int* __restrict__ cnt,
                                              const int* __restrict__ colS,
                                              const float* __restrict__ dinv,
                                              const float* __restrict__ h1,
                                              float* __restrict__ agg1, int N) {
    int i = blockIdx.x * 4 + (threadIdx.x >> 6);
    if (i >= N) return;
    int lane = threadIdx.x & 63;
    int s = off[i], n = cnt[i];
    float di = dinv[i];
    float acc = di * h1[(size_t)i * HID + lane];   // self loop (pre-factored)

    int j = 0;
    for (; j + 4 <= n; j += 4) {
        int   c0 = colS[s + j],     c1 = colS[s + j + 1];
        int   c2 = colS[s + j + 2], c3 = colS[s + j + 3];
        float w0 = dinv[c0], w1 = dinv[c1], w2 = dinv[c2], w3 = dinv[c3];
        acc += h1[(size_t)c0 * HID + lane] * w0;
        acc += h1[(size_t)c1 * HID + lane] * w1;
        acc += h1[(size_t)c2 * HID + lane] * w2;
        acc += h1[(size_t)c3 * HID + lane] * w3;
    }
    for (; j < n; ++j) {
        int c = colS[s + j];
        acc += h1[(size_t)c * HID + lane] * dinv[c];
    }
    agg1[(size_t)i * HID + lane] = di * acc;
}

// ================= GEMM2 fused: h2 = relu(agg1 + b1) @ W2 =================

__global__ __launch_bounds__(256) void k_gemm2(const float* __restrict__ agg1,
                                               const float* __restrict__ b1,
                                               const float* __restrict__ W2,
                                               float* __restrict__ h2) {
    __shared__ float Ws[HID * NC];
    __shared__ float hs[16][HID + 4];
    const int tid = threadIdx.x;

#pragma unroll
    for (int i = 0; i < 4; ++i) Ws[tid + i * 256] = W2[tid + i * 256];

    const int n0 = blockIdx.x * 16;
    {
        float4 v = ((const float4*)(agg1 + (size_t)n0 * HID))[tid];
        int n  = tid >> 4;
        int k0 = (tid & 15) << 2;
        float4 bb = *(const float4*)(b1 + k0);
        v.x = fmaxf(v.x + bb.x, 0.f);
        v.y = fmaxf(v.y + bb.y, 0.f);
        v.z = fmaxf(v.z + bb.z, 0.f);
        v.w = fmaxf(v.w + bb.w, 0.f);
        *(float4*)&hs[n][k0] = v;
    }
    __syncthreads();

    const int n = tid >> 4;
    const int c = tid & 15;
    float acc = 0.f;
#pragma unroll
    for (int k = 0; k < HID; ++k) {
        acc += hs[n][k] * Ws[k * NC + c];
    }
    h2[(size_t)(n0 + n) * NC + c] = acc;
}

// ================= agg2: gather-reduce, wave per node, 16 feats x 4 edges =================

__global__ __launch_bounds__(256) void k_agg2(const int* __restrict__ off,
                                              const int* __restrict__ cnt,
                                              const int* __restrict__ colS,
                                              const float* __restrict__ dinv,
                                              const float* __restrict__ h2,
                                              float* __restrict__ agg2, int N) {
    int i = blockIdx.x * 4 + (threadIdx.x >> 6);
    if (i >= N) return;
    int lane = threadIdx.x & 63;
    int f = lane & 15;          // feature
    int k = lane >> 4;          // edge phase 0..3
    int s = off[i], n = cnt[i];

    float acc = 0.f;
    for (int j = k; j < n; j += 4) {
        int c = colS[s + j];
        acc += h2[(size_t)c * NC + f] * dinv[c];
    }
    acc += __shfl_xor(acc, 16, 64);
    acc += __shfl_xor(acc, 32, 64);
    if (k == 0) {
        float di = dinv[i];
        agg2[(size_t)i * NC + f] = di * (acc + di * h2[(size_t)i * NC + f]);
    }
}

// ================= final: out = log_softmax(agg2 + b2) =================

__global__ __launch_bounds__(256) void k_final(const float* __restrict__ agg2,
                                               const float* __restrict__ b2,
                                               float* __restrict__ out, int N) {
    int i = blockIdx.x * blockDim.x + threadIdx.x;
    if (i >= N) return;
    float v[NC];
    const float4* src = (const float4*)(agg2 + (size_t)i * NC);
#pragma unroll
    for (int q = 0; q < 4; ++q) {
        float4 t = src[q];
        v[q * 4 + 0] = t.x + b2[q * 4 + 0];
        v[q * 4 + 1] = t.y + b2[q * 4 + 1];
        v[q * 4 + 2] = t.z + b2[q * 4 + 2];
        v[q * 4 + 3] = t.w + b2[q * 4 + 3];
    }
    float m = v[0];
#pragma unroll
    for (int c = 1; c < NC; ++c) m = fmaxf(m, v[c]);
    float s = 0.f;
#pragma unroll
    for (int c = 0; c < NC; ++c) s += expf(v[c] - m);
    float ls = logf(s);
    float4* dst = (float4*)(out + (size_t)i * NC);
#pragma unroll
    for (int q = 0; q < 4; ++q) {
        float4 t;
        t.x = v[q * 4 + 0] - m - ls;
        t.y = v[q * 4 + 1] - m - ls;
        t.z = v[q * 4 + 2] - m - ls;
        t.w = v[q * 4 + 3] - m - ls;
        dst[q] = t;
    }
}

// ================= launch =================

extern "C" void kernel_launch(void* const* d_in, const int* in_sizes, int n_in,
                              void* d_out, int out_size, void* d_ws, size_t ws_size,
                              hipStream_t stream) {
    const float* x  = (const float*)d_in[0];
    const int*   ei = (const int*)d_in[1];
    const float* W1 = (const float*)d_in[2];
    const float* b1 = (const float*)d_in[3];
    const float* W2 = (const float*)d_in[4];
    const float* b2 = (const float*)d_in[5];
    float* out = (float*)d_out;

    const int N = in_sizes[0] / FIN;        // 50000
    const int E = in_sizes[1] / 2;          // 1600000
    const int* row = ei;                    // targets
    const int* col = ei + E;                // sources
    const int NB = (N + 255) >> 8;          // 196 buckets (<=256)

    // ---- workspace layout ----
    char* w = (char*)d_ws;
    int*   cnt    = (int*)w;                w += (size_t)N * 4;
    int*   off    = (int*)w;                w += (size_t)N * 4;
    int*   cur    = (int*)w;                w += (size_t)N * 4;
    int*   offtmp = (int*)w;                w += (size_t)N * 4;
    int*   bsum   = (int*)w;                w += 256 * 4;
    int*   bcur   = (int*)w;                w += 256 * 4;
    int*   colS   = (int*)w;                w += (size_t)E * 4;
    float* dinv   = (float*)w;              w += (size_t)N * 4;
    float* h1     = (float*)w;              w += (size_t)N * HID * 4;
    float* agg1   = (float*)w;              w += (size_t)N * HID * 4;
    float* h2     = (float*)w;              w += (size_t)N * NC * 4;
    float* agg2   = (float*)w;              w += (size_t)N * NC * 4;
    // stage (E int2 = 12.8MB) overlays h1+agg1 (25.6MB): dead before k_gemm1 writes h1
    int2*  stage  = (int2*)h1;

    const int B = 256;
    const int nbN = (N + B - 1) / B;   // 196

    hipMemsetAsync(cnt, 0, (size_t)N * 4, stream);
    k_hist<<<(E + B - 1) / B, B, 0, stream>>>(row, cnt, E);
    k_dinv<<<nbN, B, 0, stream>>>(cnt, dinv, N);

    k_scan_block<<<nbN, B, 0, stream>>>(cnt, offtmp, bsum, N);
    k_scan_bsum<<<1, B, 0, stream>>>(bsum, nbN);
    k_off<<<nbN, B, 0, stream>>>(offtmp, bsum, off, cur, N);
    k_bstart<<<1, B, 0, stream>>>(off, bcur, NB);

    k_bin<<<(E + BIN_CHUNK - 1) / BIN_CHUNK, B, 0, stream>>>(row, col, bcur, stage, E);
    k_place<<<(E + B - 1) / B, B, 0, stream>>>(stage, cur, colS, E);

    k_gemm1<<<N / 16, B, 0, stream>>>(x, W1, h1);
    k_agg1<<<(N + 3) / 4, B, 0, stream>>>(off, cnt, colS, dinv, h1, agg1, N);

    k_gemm2<<<N / 16, B, 0, stream>>>(agg1, b1, W2, h2);
    k_agg2<<<(N + 3) / 4, B, 0, stream>>>(off, cnt, colS, dinv, h2, agg2, N);

    k_final<<<nbN, B, 0, stream>>>(agg2, b2, out, N);
}